// Round 10
// baseline (531.502 us; speedup 1.0000x reference)
//
#include <hip/hip_runtime.h>

typedef _Float16 half_t;
typedef __attribute__((ext_vector_type(8))) _Float16 half8;
typedef __attribute__((ext_vector_type(4))) float floatx4;

// ---------------------------------------------------------------------------
// Round 14: fix grid-limited gemm occupancy (L2/L3 were 1024 blocks = 4/CU,
// measured 33% occ): M-tile 64 -> 32 pixels/block, doubling every gemm grid
// to >=2048 blocks (8/CU). Per-block state halves (acc 16 VGPR, r/u 16,
// LDS As 4KB) -> 8 blocks/CU feasible; __launch_bounds__(256,8) pins
// VGPR <= 64 (occupancy cliff at 64). ln_prep reverted to R12's form
// (R13's chan_ss/pix_stats diet measured neutral-to-negative).
// Everything else (recurrence A-gen, pre-swizzled gload_lds B, z-slab
// split-K, bn kernels) unchanged from the 477us best.
// ---------------------------------------------------------------------------

#define RBF_SCALE 2.1019644f       // 1.75 * sqrt(log2 e)
#define RBF_G0   -4.2039288f       // RBF_SCALE * (-2)
#define RBF_2D    2.40224482f      // 2*sqrt(log2 e)
#define RBF_D2    1.44269504f      // log2 e
#define RBF_Q     0.13533528f      // e^-2

// ---- patch gather (LDS-staged) + LayerNorm -> pn' (fp16), silu (R12) ----
// block: 4 consecutive-in-x pixels (same row; W%4==0), 1 wave each.
template<int C, int H, int W>
__global__ __launch_bounds__(256)
void ln_prep(const float* __restrict__ x,
             const float* __restrict__ lnw, const float* __restrict__ lnb,
             half_t* __restrict__ pn, half_t* __restrict__ sp)
{
    const int HW = H * W, IN = C * 9;
    const int NL = (IN + 63) / 64;
    __shared__ float xw[C * 18];                 // [C][3][6]

    const int wv = threadIdx.x >> 6, lane = threadIdx.x & 63;
    const int pix0 = blockIdx.x * 4;
    const int b = pix0 / HW, hw0 = pix0 % HW;
    const int h = hw0 / W, x0 = hw0 % W;         // pixels x0..x0+3, same row
    const float* xb = x + (long)b * C * HW;

    // ---- cooperative stage: window cols x0-1 .. x0+4, rows h-1..h+1 ----
    for (int idx = threadIdx.x; idx < C * 18; idx += 256) {
        int ch = idx / 18, rem = idx - ch * 18;
        int dy = rem / 6, dx = rem - dy * 6;
        int y = h + dy - 1, xx = x0 + dx - 1;
        float v = 0.f;
        if (y >= 0 && y < H && xx >= 0 && xx < W)
            v = xb[(long)ch * HW + y * W + xx];
        xw[idx] = v;
    }
    __syncthreads();

    const int pix = pix0 + wv;

    float v[NL];
    float s = 0.f, s2 = 0.f;
    #pragma unroll
    for (int t = 0; t < NL; ++t) {
        int i = t * 64 + lane;
        float val = 0.f;
        if (i < IN) {
            int ch = i / 9, r = i - ch * 9;
            int dy = r / 3, dx = r - dy * 3;
            val = xw[ch * 18 + dy * 6 + wv + dx];
        }
        v[t] = val; s += val; s2 += val * val;
    }
    #pragma unroll
    for (int off = 32; off > 0; off >>= 1) {
        s  += __shfl_down(s,  off, 64);
        s2 += __shfl_down(s2, off, 64);
    }
    s = __shfl(s, 0, 64); s2 = __shfl(s2, 0, 64);
    float mean = s / IN;
    float istd = rsqrtf(s2 / IN - mean * mean + 1e-5f);

    #pragma unroll
    for (int t = 0; t < NL; ++t) {
        int i = t * 64 + lane;
        if (i < IN) {
            float val = v[t];
            float pnv = (val - mean) * istd * lnw[i] + lnb[i];
            pnv = fminf(12.f, fmaxf(-12.f, pnv * RBF_SCALE));   // clamp for recurrence
            pn[(long)pix * IN + i] = (half_t)pnv;
            sp[(long)pix * IN + i] = (half_t)(val / (1.f + __expf(-val)));
        }
    }
}

// ---- fp32 weights -> fp16 packed [step][OUT][64], XOR pre-swizzle ----
// step s -> iblk = s/9, j = s%9; packed col uu holds k-unit (uu>>3)^(o&7):
// i = iblk*64 + ((uu>>3)^(o&7))*8 + (uu&7); k = j*IN + i (j<8 Ws, j==8 Wb).
template<int IN, int OUT>
__global__ __launch_bounds__(256)
void conv_w(const float* __restrict__ Ws, const float* __restrict__ Wb,
            half_t* __restrict__ Wt)
{
    const int NIB = (IN + 63) / 64, NSTEP = NIB * 9;
    int idx = blockIdx.x * 256 + threadIdx.x;
    if (idx >= OUT * NSTEP * 64) return;
    int uu = idx & 63;
    int t = idx >> 6;
    int o = t % OUT;
    int s = t / OUT;
    int iblk = s / 9, j = s % 9;
    int ulin = (((uu >> 3) ^ (o & 7)) << 3) + (uu & 7);
    int i = iblk * 64 + ulin;
    float v = 0.f;
    if (i < IN)
        v = (j < 8) ? Ws[(long)o * IN * 8 + i * 8 + j] : Wb[(long)o * IN + i];
    Wt[idx] = (half_t)v;
}

// ---- fused A-gen + MFMA GEMM, M=32 tile (2-barrier loop + prefetch) ----
// block: 32 pixels x (4*NB*16) outputs at yoff; wave wv: NB*16 outputs.
// thread (row=tid>>3, q=tid&7): one 8-elem chunk of the 32x64 A tile.
// B via global_load_lds (linear dest, pre-swizzled source). A swizzled write.
// LDS XOR swizzle: 16B unit w at w ^ (row & 7), row stride 64 halfs.
template<int IN, int OUT, int HW, int NB, int SPLIT>
__global__ __launch_bounds__(256, 8)
void kan_gemm(const half_t* __restrict__ pn, const half_t* __restrict__ sp,
              const half_t* __restrict__ Wt, float* __restrict__ out)
{
    const int NIB = (IN + 63) / 64;

    __shared__ half_t As[32 * 64];               // 4 KB
    __shared__ half_t Bs[NB * 64 * 64];          // NB * 8 KB

    const int tid = threadIdx.x;
    const int row = tid >> 3, q = tid & 7;       // 32 rows x 8 chunks
    const int pix = blockIdx.x * 32 + row;
    const half_t* pnrow = pn + (long)pix * IN;
    const half_t* sprow = sp + (long)pix * IN;

    const int wv = tid >> 6, lane = tid & 63;
    const int lr = lane & 15, lq = lane >> 4;
    const int u0 = q ^ (row & 7);                // swizzled 16B unit (A stage)
    const int yoff = blockIdx.y * (4 * NB * 16);

    floatx4 acc[NB][2] = {};
    float r[8], u[8];
    half8 pf;                                    // global prefetch

    const int grpA = (blockIdx.z * NIB) / SPLIT;         // group-aligned split
    const int grpB = ((blockIdx.z + 1) * NIB) / SPLIT;
    const int s0 = grpA * 9, s1 = grpB * 9;

    int jg = 0, ibg = grpA;    // A-gen state: next step to generate

    // clamped-address global load (tail chunks: weights are zero there, and
    // clamped pn in [-12,12] keeps the recurrence finite)
    auto ldglob = [&](const half_t* base, int ib, half8& a) {
        int i0 = ib * 64 + q * 8;
        a = *(const half8*)(base + ((i0 < IN) ? i0 : 0));
    };

    auto stageB = [&](int it) {
        const half_t* wsrc = Wt + (long)it * OUT * 64
                              + (long)(yoff + wv * NB * 16) * 64;
        #pragma unroll
        for (int c = 0; c < NB * 2; ++c) {
            __builtin_amdgcn_global_load_lds(
                (const __attribute__((address_space(1))) void*)(wsrc + c * 512 + lane * 8),
                (__attribute__((address_space(3))) void*)(&Bs[wv * NB * 1024 + c * 512]),
                16, 0, 0);
        }
    };

    auto genA = [&]() {
        if (jg < 8) {
            if (jg == 0) {
                // pf holds pn(ibg), prefetched at previous jg==8 (or prologue)
                #pragma unroll
                for (int kk = 0; kk < 8; ++kk) {
                    float d = (float)pf[kk] - RBF_G0;
                    r[kk] = __builtin_amdgcn_exp2f(-(d * d));
                    u[kk] = __builtin_amdgcn_exp2f(fmaf(RBF_2D, d, -RBF_D2));
                }
            }
            half8 a;
            #pragma unroll
            for (int kk = 0; kk < 8; ++kk) a[kk] = (half_t)r[kk];
            *(half8*)&As[row * 64 + u0 * 8] = a;
            if (jg < 7) {
                #pragma unroll
                for (int kk = 0; kk < 8; ++kk) { r[kk] *= u[kk]; u[kk] *= RBF_Q; }
            }
            if (jg == 7) ldglob(sprow, ibg, pf);            // prefetch silu
        } else {
            // pf holds sp(ibg), prefetched at jg==7
            *(half8*)&As[row * 64 + u0 * 8] = pf;
            ldglob(pnrow, ibg + 1, pf);                     // prefetch next pn
        }
        if (++jg == 9) { jg = 0; ++ibg; }
    };

    auto domfma = [&]() {
        __builtin_amdgcn_s_setprio(1);
        #pragma unroll
        for (int ks = 0; ks < 2; ++ks) {
            half8 af[2], bf[NB];
            #pragma unroll
            for (int mf = 0; mf < 2; ++mf) {
                int rr = mf * 16 + lr;
                af[mf] = *(const half8*)&As[rr * 64 + (((ks * 4 + lq) ^ (rr & 7)) * 8)];
            }
            #pragma unroll
            for (int nb = 0; nb < NB; ++nb) {
                int rr = wv * NB * 16 + nb * 16 + lr;
                bf[nb] = *(const half8*)&Bs[rr * 64 + (((ks * 4 + lq) ^ (rr & 7)) * 8)];
            }
            #pragma unroll
            for (int nb = 0; nb < NB; ++nb)
                #pragma unroll
                for (int mf = 0; mf < 2; ++mf)
                    acc[nb][mf] = __builtin_amdgcn_mfma_f32_16x16x32_f16(
                        bf[nb], af[mf], acc[nb][mf], 0, 0, 0);
        }
        __builtin_amdgcn_s_setprio(0);
    };

    // ---- prologue: prefetch pn(grpA) ----
    ldglob(pnrow, grpA, pf);

    // ---- main loop: stage (async) + A-gen, barrier, MFMA ----
    for (int it = s0; it < s1; ++it) {
        __syncthreads();           // previous MFMA reads done
        stageB(it);                // async gload_lds -> Bs
        genA();                    // VALU + swizzled ds_write -> As
        __syncthreads();           // drain: As/Bs ready
        domfma();
    }

    // ---- epilogue: plain stores into z-partial slab ----
    const long zoff = (long)blockIdx.z * ((long)gridDim.x * 32) * OUT;
    #pragma unroll
    for (int nb = 0; nb < NB; ++nb)
    #pragma unroll
    for (int mf = 0; mf < 2; ++mf)
    #pragma unroll
    for (int reg = 0; reg < 4; ++reg) {
        int o  = yoff + wv * NB * 16 + nb * 16 + lq * 4 + reg;
        int p2 = blockIdx.x * 32 + mf * 16 + lr;
        int b2 = p2 / HW, hw2 = p2 % HW;
        out[zoff + ((long)b2 * OUT + o) * HW + hw2] = acc[nb][mf][reg];
    }
}

// ---- BatchNorm batch-stats over summed z-partials (bias folded in) ----
__launch_bounds__(256)
__global__ void bn_stats(const float* __restrict__ h, const float* __restrict__ bias,
                         int C, int HW, int B, int nz, float* __restrict__ sums)
{
    int c = blockIdx.y;
    float bbc = bias[c];
    long zstride = (long)B * C * HW;
    int total = B * HW;
    float s = 0.f, s2 = 0.f;
    for (int idx = blockIdx.x * 256 + threadIdx.x; idx < total; idx += 256 * gridDim.x) {
        int b = idx / HW, r = idx % HW;
        long base = ((long)b * C + c) * HW + r;
        float v = bbc;
        for (int z = 0; z < nz; ++z) v += h[z * zstride + base];
        s += v; s2 += v * v;
    }
    for (int off = 32; off > 0; off >>= 1) {
        s  += __shfl_down(s,  off, 64);
        s2 += __shfl_down(s2, off, 64);
    }
    __shared__ float rs[4], rs2[4];
    int lane = threadIdx.x & 63, wid = threadIdx.x >> 6;
    if (lane == 0) { rs[wid] = s; rs2[wid] = s2; }
    __syncthreads();
    if (threadIdx.x == 0) {
        atomicAdd(&sums[c],     rs[0] + rs[1] + rs[2] + rs[3]);
        atomicAdd(&sums[C + c], rs2[0] + rs2[1] + rs2[2] + rs2[3]);
    }
}

__launch_bounds__(256)
__global__ void bn_relu_pool(const float* __restrict__ h, const float* __restrict__ sums,
                             const float* __restrict__ bias,
                             const float* __restrict__ gamma, const float* __restrict__ beta,
                             float* __restrict__ out, int B, int C, int H, int W, int nz)
{
    int Ho = H / 2, Wo = W / 2;
    long total = (long)B * C * Ho * Wo;
    long idx = (long)blockIdx.x * 256 + threadIdx.x;
    if (idx >= total) return;
    int pw = idx % Wo; long t = idx / Wo;
    int ph = t % Ho; t /= Ho;
    int c = t % C; int b = (int)(t / C);

    float M = (float)B * H * W;
    float mean = sums[c] / M;
    float var  = sums[C + c] / M - mean * mean;
    float scale = gamma[c] * rsqrtf(var + 1e-5f);
    float shift = beta[c] - mean * scale + bias[c] * scale;  // fold conv bias

    long zstride = (long)B * C * H * W;
    const float* hp = h + ((long)b * C + c) * H * W;
    float m = 0.f;  // post-relu >= 0
    #pragma unroll
    for (int i = 0; i < 2; ++i)
        #pragma unroll
        for (int j = 0; j < 2; ++j) {
            long off = (2 * ph + i) * W + 2 * pw + j;
            float v = 0.f;
            for (int z = 0; z < nz; ++z) v += hp[z * zstride + off];
            v = v * scale + shift;
            m = fmaxf(m, v);
        }
    out[idx] = m;
}

extern "C" void kernel_launch(void* const* d_in, const int* in_sizes, int n_in,
                              void* d_out, int out_size, void* d_ws, size_t ws_size,
                              hipStream_t stream) {
    const float* x     = (const float*)d_in[0];
    const float* ln_w1 = (const float*)d_in[1];  const float* ln_b1 = (const float*)d_in[2];
    const float* Wb1   = (const float*)d_in[3];  const float* bb1   = (const float*)d_in[4];
    const float* Ws1   = (const float*)d_in[5];  const float* g1    = (const float*)d_in[6];
    const float* be1   = (const float*)d_in[7];
    const float* ln_w2 = (const float*)d_in[8];  const float* ln_b2 = (const float*)d_in[9];
    const float* Wb2   = (const float*)d_in[10]; const float* bb2   = (const float*)d_in[11];
    const float* Ws2   = (const float*)d_in[12]; const float* g2    = (const float*)d_in[13];
    const float* be2   = (const float*)d_in[14];
    const float* ln_w3 = (const float*)d_in[15]; const float* ln_b3 = (const float*)d_in[16];
    const float* Wb3   = (const float*)d_in[17]; const float* bb3   = (const float*)d_in[18];
    const float* Ws3   = (const float*)d_in[19]; const float* g3    = (const float*)d_in[20];
    const float* be3   = (const float*)d_in[21];

    const int B = 32;
    char* ws = (char*)d_ws;
    float*  convbuf = (float*)(ws + 0);              // 33,554,432 (z-partials L2/L3)
    float*  poolbuf = (float*)(ws + 33554432);       //  8,388,608
    float*  stats1  = (float*)(ws + 41943040);       //  2048 x3
    float*  stats2  = (float*)(ws + 41945088);
    float*  stats3  = (float*)(ws + 41947136);
    half_t* wt1     = (half_t*)(ws + 41949184);      //   221,184  (27 x 64 x 64)
    half_t* wt2     = (half_t*)(ws + 42170368);      // 1,327,104  (81 x 128 x 64)
    half_t* wt3     = (half_t*)(ws + 43497472);      // 5,308,416  (162 x 256 x 64)
    half_t* pnbuf   = (half_t*)(ws + 48805888);      // 37,748,736 (max 131072x144)
    half_t* spbuf   = (half_t*)(ws + 86554624);      // 37,748,736
    // total: 124,303,360 B

    hipMemsetAsync(stats1, 0, 6144, stream);

    conv_w<144, 64><<<(64 * 27 * 64 + 255) / 256, 256, 0, stream>>>(Ws1, Wb1, wt1);
    conv_w<576, 128><<<(128 * 81 * 64 + 255) / 256, 256, 0, stream>>>(Ws2, Wb2, wt2);
    conv_w<1152, 256><<<(256 * 162 * 64 + 255) / 256, 256, 0, stream>>>(Ws3, Wb3, wt3);

    // ---------------- layer 1: C=16, H=W=64, OUT=64, NB=1, y=1, z=1 ---------
    {
        const int H = 64, W = 64, OUT = 64;
        int npix = B * H * W;                    // 131072
        ln_prep<16, H, W><<<npix / 4, 256, 0, stream>>>(x, ln_w1, ln_b1, pnbuf, spbuf);
        kan_gemm<144, OUT, H * W, 1, 1><<<dim3(npix / 32, 1, 1), 256, 0, stream>>>(
            pnbuf, spbuf, wt1, convbuf);
        bn_stats<<<dim3(64, OUT), 256, 0, stream>>>(convbuf, bb1, OUT, H * W, B, 1, stats1);
        long tot = (long)B * OUT * (H / 2) * (W / 2);
        bn_relu_pool<<<(tot + 255) / 256, 256, 0, stream>>>(
            convbuf, stats1, bb1, g1, be1, poolbuf, B, OUT, H, W, 1);
    }
    // ---------------- layer 2: C=64, H=W=32, OUT=128, NB=2, y=1, z=2 --------
    {
        const int H = 32, W = 32, OUT = 128;
        int npix = B * H * W;                    // 32768
        ln_prep<64, H, W><<<npix / 4, 256, 0, stream>>>(poolbuf, ln_w2, ln_b2, pnbuf, spbuf);
        kan_gemm<576, OUT, H * W, 2, 2><<<dim3(npix / 32, 1, 2), 256, 0, stream>>>(
            pnbuf, spbuf, wt2, convbuf);           // 2 x 16.8 MB partials in convbuf
        bn_stats<<<dim3(16, OUT), 256, 0, stream>>>(convbuf, bb2, OUT, H * W, B, 2, stats2);
        long tot = (long)B * OUT * (H / 2) * (W / 2);
        bn_relu_pool<<<(tot + 255) / 256, 256, 0, stream>>>(
            convbuf, stats2, bb2, g2, be2, poolbuf, B, OUT, H, W, 2);
    }
    // ---------------- layer 3: C=128, H=W=16, OUT=256, NB=2, y=2, z=4 -------
    {
        const int H = 16, W = 16, OUT = 256;
        int npix = B * H * W;                    // 8192
        ln_prep<128, H, W><<<npix / 4, 256, 0, stream>>>(poolbuf, ln_w3, ln_b3, pnbuf, spbuf);
        kan_gemm<1152, OUT, H * W, 2, 4><<<dim3(npix / 32, 2, 4), 256, 0, stream>>>(
            pnbuf, spbuf, wt3, convbuf);           // 4 x 8.4 MB partials in convbuf
        bn_stats<<<dim3(8, OUT), 256, 0, stream>>>(convbuf, bb3, OUT, H * W, B, 4, stats3);
        long tot = (long)B * OUT * (H / 2) * (W / 2);  // 524288 == out_size
        bn_relu_pool<<<(tot + 255) / 256, 256, 0, stream>>>(
            convbuf, stats3, bb3, g3, be3, (float*)d_out, B, OUT, H, W, 4);
    }
}

// Round 11
// 465.567 us; speedup vs baseline: 1.1416x; 1.1416x over previous
//
#include <hip/hip_runtime.h>

typedef _Float16 half_t;
typedef __attribute__((ext_vector_type(8))) _Float16 half8;
typedef __attribute__((ext_vector_type(4))) float floatx4;

// ---------------------------------------------------------------------------
// Round 15: gemm reverted to R12's exact M=64 form (R14 falsified the
// occupancy theory: M=32 raised occ 33->65% but slowed gemm 67->85us by
// worsening LDS frag-reads/FLOP). New single change: ln_prep processes
// 16 pixels/block (4/wave sequential) -- 4x fewer blocks, window staged
// once per block, gather addresses hoisted, LDS row padded to 19 (bank
// spread). ln_prep was 145-155us of 477 with ~75% VALUBusy from per-block
// overhead, not useful work.
// ---------------------------------------------------------------------------

#define RBF_SCALE 2.1019644f       // 1.75 * sqrt(log2 e)
#define RBF_G0   -4.2039288f       // RBF_SCALE * (-2)
#define RBF_2D    2.40224482f      // 2*sqrt(log2 e)
#define RBF_D2    1.44269504f      // log2 e
#define RBF_Q     0.13533528f      // e^-2

// ---- patch gather + LayerNorm -> pn' (fp16), silu; 16 pixels/block ----
// block: 16 consecutive-in-x pixels (same row; W%16==0). Wave wv handles
// pixels wv*4..wv*4+3 sequentially. Window [C][3][19] staged once.
template<int C, int H, int W>
__global__ __launch_bounds__(256)
void ln_prep(const float* __restrict__ x,
             const float* __restrict__ lnw, const float* __restrict__ lnb,
             half_t* __restrict__ pn, half_t* __restrict__ sp)
{
    const int HW = H * W, IN = C * 9;
    const int NL = (IN + 63) / 64;
    __shared__ float xw[C * 57];                 // [C][3][19], cols 0..17 used

    const int wv = threadIdx.x >> 6, lane = threadIdx.x & 63;
    const int pix0 = blockIdx.x * 16;
    const int b = pix0 / HW, hw0 = pix0 % HW;
    const int h = hw0 / W, x0 = hw0 % W;         // pixels x0..x0+15, same row
    const float* xb = x + (long)b * C * HW;

    // ---- cooperative stage: cols x0-1 .. x0+16, rows h-1..h+1 ----
    for (int idx = threadIdx.x; idx < C * 54; idx += 256) {
        int ch = idx / 54, rem = idx - ch * 54;
        int dy = rem / 18, col = rem - dy * 18;
        int y = h + dy - 1, xx = x0 + col - 1;
        float v = 0.f;
        if (y >= 0 && y < H && xx >= 0 && xx < W)
            v = xb[(long)ch * HW + y * W + xx];
        xw[ch * 57 + dy * 19 + col] = v;
    }
    __syncthreads();

    // ---- hoisted per-lane gather addresses and LN params ----
    int  ga[NL];
    float lw[NL], lb[NL];
    #pragma unroll
    for (int t = 0; t < NL; ++t) {
        int i = t * 64 + lane;
        if (i < IN) {
            int ch = i / 9, r = i - ch * 9;
            int dy = r / 3, dx = r - dy * 3;
            ga[t] = ch * 57 + dy * 19 + dx;
            lw[t] = lnw[i];
            lb[t] = lnb[i];
        } else { ga[t] = 0; lw[t] = 0.f; lb[t] = 0.f; }
    }

    #pragma unroll
    for (int p = 0; p < 4; ++p) {
        const int px = wv * 4 + p;               // 0..15
        const int pix = pix0 + px;

        float v[NL];
        float s = 0.f, s2 = 0.f;
        #pragma unroll
        for (int t = 0; t < NL; ++t) {
            int i = t * 64 + lane;
            float val = (i < IN) ? xw[ga[t] + px] : 0.f;
            v[t] = val; s += val; s2 += val * val;
        }
        #pragma unroll
        for (int off = 32; off > 0; off >>= 1) {
            s  += __shfl_down(s,  off, 64);
            s2 += __shfl_down(s2, off, 64);
        }
        s = __shfl(s, 0, 64); s2 = __shfl(s2, 0, 64);
        float mean = s / IN;
        float istd = rsqrtf(s2 / IN - mean * mean + 1e-5f);

        #pragma unroll
        for (int t = 0; t < NL; ++t) {
            int i = t * 64 + lane;
            if (i < IN) {
                float val = v[t];
                float pnv = (val - mean) * istd * lw[t] + lb[t];
                pnv = fminf(12.f, fmaxf(-12.f, pnv * RBF_SCALE));  // clamp
                pn[(long)pix * IN + i] = (half_t)pnv;
                sp[(long)pix * IN + i] = (half_t)(val / (1.f + __expf(-val)));
            }
        }
    }
}

// ---- fp32 weights -> fp16 packed [step][OUT][64], XOR pre-swizzle ----
// step s -> iblk = s/9, j = s%9; packed col uu holds k-unit (uu>>3)^(o&7):
// i = iblk*64 + ((uu>>3)^(o&7))*8 + (uu&7); k = j*IN + i (j<8 Ws, j==8 Wb).
template<int IN, int OUT>
__global__ __launch_bounds__(256)
void conv_w(const float* __restrict__ Ws, const float* __restrict__ Wb,
            half_t* __restrict__ Wt)
{
    const int NIB = (IN + 63) / 64, NSTEP = NIB * 9;
    int idx = blockIdx.x * 256 + threadIdx.x;
    if (idx >= OUT * NSTEP * 64) return;
    int uu = idx & 63;
    int t = idx >> 6;
    int o = t % OUT;
    int s = t / OUT;
    int iblk = s / 9, j = s % 9;
    int ulin = (((uu >> 3) ^ (o & 7)) << 3) + (uu & 7);
    int i = iblk * 64 + ulin;
    float v = 0.f;
    if (i < IN)
        v = (j < 8) ? Ws[(long)o * IN * 8 + i * 8 + j] : Wb[(long)o * IN + i];
    Wt[idx] = (half_t)v;
}

// ---- fused A-gen + MFMA GEMM (R12: 2-barrier loop + prefetch, M=64) ----
// block: 64 pixels x (4*NB*16) outputs at yoff; wave wv: NB*16 outputs.
// B via global_load_lds (linear dest, pre-swizzled source). A swizzled writes.
// LDS XOR swizzle: 16B unit w at w ^ (row & 7), row stride 64 halfs.
template<int IN, int OUT, int HW, int NB, int SPLIT>
__global__ __launch_bounds__(256)
void kan_gemm(const half_t* __restrict__ pn, const half_t* __restrict__ sp,
              const half_t* __restrict__ Wt, float* __restrict__ out)
{
    const int NIB = (IN + 63) / 64;

    __shared__ half_t As[64 * 64];
    __shared__ half_t Bs[NB * 64 * 64];

    const int tid = threadIdx.x;
    const int row = tid >> 2, q = tid & 3;
    const int pix = blockIdx.x * 64 + row;
    const half_t* pnrow = pn + (long)pix * IN;
    const half_t* sprow = sp + (long)pix * IN;

    const int wv = tid >> 6, lane = tid & 63;
    const int lr = lane & 15, lq = lane >> 4;
    const int u0 = (2 * q) ^ (row & 7);         // swizzled 16B units (A stage)
    const int u1 = (2 * q + 1) ^ (row & 7);
    const int yoff = blockIdx.y * (4 * NB * 16);

    floatx4 acc[NB][4] = {};
    float r[16], u[16];
    half8 pf0, pf1;                              // global prefetch pair

    const int grpA = (blockIdx.z * NIB) / SPLIT;         // group-aligned split
    const int grpB = ((blockIdx.z + 1) * NIB) / SPLIT;
    const int s0 = grpA * 9, s1 = grpB * 9;

    int jg = 0, ibg = grpA;    // A-gen state: next step to generate

    // clamped-address global load (tail chunks: weights are zero there, and
    // clamped pn in [-12,12] keeps the recurrence finite)
    auto ldglob = [&](const half_t* base, int ib, half8& a, half8& b) {
        int i0 = ib * 64 + q * 16;
        const half_t* pp = base + ((i0 < IN) ? i0 : 0);
        a = *(const half8*)pp;
        b = *(const half8*)(pp + 8);
    };

    auto stageB = [&](int it) {
        const half_t* wsrc = Wt + (long)it * OUT * 64
                              + (long)(yoff + wv * NB * 16) * 64;
        #pragma unroll
        for (int c = 0; c < NB * 2; ++c) {
            __builtin_amdgcn_global_load_lds(
                (const __attribute__((address_space(1))) void*)(wsrc + c * 512 + lane * 8),
                (__attribute__((address_space(3))) void*)(&Bs[wv * NB * 1024 + c * 512]),
                16, 0, 0);
        }
    };

    auto genA = [&]() {
        if (jg < 8) {
            if (jg == 0) {
                // pf holds pn(ibg), prefetched at previous jg==8 (or prologue)
                #pragma unroll
                for (int kk = 0; kk < 8; ++kk) {
                    float d0 = (float)pf0[kk] - RBF_G0;
                    float d1 = (float)pf1[kk] - RBF_G0;
                    r[kk]     = __builtin_amdgcn_exp2f(-(d0 * d0));
                    u[kk]     = __builtin_amdgcn_exp2f(fmaf(RBF_2D, d0, -RBF_D2));
                    r[kk + 8] = __builtin_amdgcn_exp2f(-(d1 * d1));
                    u[kk + 8] = __builtin_amdgcn_exp2f(fmaf(RBF_2D, d1, -RBF_D2));
                }
            }
            half8 a0, a1;
            #pragma unroll
            for (int kk = 0; kk < 8; ++kk) {
                a0[kk] = (half_t)r[kk];
                a1[kk] = (half_t)r[kk + 8];
            }
            *(half8*)&As[row * 64 + u0 * 8] = a0;
            *(half8*)&As[row * 64 + u1 * 8] = a1;
            if (jg < 7) {
                #pragma unroll
                for (int kk = 0; kk < 16; ++kk) { r[kk] *= u[kk]; u[kk] *= RBF_Q; }
            }
            if (jg == 7) ldglob(sprow, ibg, pf0, pf1);      // prefetch silu
        } else {
            // pf holds sp(ibg), prefetched at jg==7
            *(half8*)&As[row * 64 + u0 * 8] = pf0;
            *(half8*)&As[row * 64 + u1 * 8] = pf1;
            ldglob(pnrow, ibg + 1, pf0, pf1);               // prefetch next pn
        }
        if (++jg == 9) { jg = 0; ++ibg; }
    };

    auto domfma = [&]() {
        __builtin_amdgcn_s_setprio(1);
        #pragma unroll
        for (int ks = 0; ks < 2; ++ks) {
            half8 af[4], bf[NB];
            #pragma unroll
            for (int mf = 0; mf < 4; ++mf) {
                int rr = mf * 16 + lr;
                af[mf] = *(const half8*)&As[rr * 64 + (((ks * 4 + lq) ^ (rr & 7)) * 8)];
            }
            #pragma unroll
            for (int nb = 0; nb < NB; ++nb) {
                int rr = wv * NB * 16 + nb * 16 + lr;
                bf[nb] = *(const half8*)&Bs[rr * 64 + (((ks * 4 + lq) ^ (rr & 7)) * 8)];
            }
            #pragma unroll
            for (int nb = 0; nb < NB; ++nb)
                #pragma unroll
                for (int mf = 0; mf < 4; ++mf)
                    acc[nb][mf] = __builtin_amdgcn_mfma_f32_16x16x32_f16(
                        bf[nb], af[mf], acc[nb][mf], 0, 0, 0);
        }
        __builtin_amdgcn_s_setprio(0);
    };

    // ---- prologue: prefetch pn(grpA) ----
    ldglob(pnrow, grpA, pf0, pf1);

    // ---- main loop: stage (async) + A-gen, barrier, MFMA ----
    for (int it = s0; it < s1; ++it) {
        __syncthreads();           // previous MFMA reads done
        stageB(it);                // async gload_lds -> Bs
        genA();                    // VALU + swizzled ds_write -> As
        __syncthreads();           // drain: As/Bs ready
        domfma();
    }

    // ---- epilogue: plain stores into z-partial slab ----
    const long zoff = (long)blockIdx.z * ((long)gridDim.x * 64) * OUT;
    #pragma unroll
    for (int nb = 0; nb < NB; ++nb)
    #pragma unroll
    for (int mf = 0; mf < 4; ++mf)
    #pragma unroll
    for (int reg = 0; reg < 4; ++reg) {
        int o  = yoff + wv * NB * 16 + nb * 16 + lq * 4 + reg;
        int p2 = blockIdx.x * 64 + mf * 16 + lr;
        int b2 = p2 / HW, hw2 = p2 % HW;
        out[zoff + ((long)b2 * OUT + o) * HW + hw2] = acc[nb][mf][reg];
    }
}

// ---- BatchNorm batch-stats over summed z-partials (bias folded in) ----
__launch_bounds__(256)
__global__ void bn_stats(const float* __restrict__ h, const float* __restrict__ bias,
                         int C, int HW, int B, int nz, float* __restrict__ sums)
{
    int c = blockIdx.y;
    float bbc = bias[c];
    long zstride = (long)B * C * HW;
    int total = B * HW;
    float s = 0.f, s2 = 0.f;
    for (int idx = blockIdx.x * 256 + threadIdx.x; idx < total; idx += 256 * gridDim.x) {
        int b = idx / HW, r = idx % HW;
        long base = ((long)b * C + c) * HW + r;
        float v = bbc;
        for (int z = 0; z < nz; ++z) v += h[z * zstride + base];
        s += v; s2 += v * v;
    }
    for (int off = 32; off > 0; off >>= 1) {
        s  += __shfl_down(s,  off, 64);
        s2 += __shfl_down(s2, off, 64);
    }
    __shared__ float rs[4], rs2[4];
    int lane = threadIdx.x & 63, wid = threadIdx.x >> 6;
    if (lane == 0) { rs[wid] = s; rs2[wid] = s2; }
    __syncthreads();
    if (threadIdx.x == 0) {
        atomicAdd(&sums[c],     rs[0] + rs[1] + rs[2] + rs[3]);
        atomicAdd(&sums[C + c], rs2[0] + rs2[1] + rs2[2] + rs2[3]);
    }
}

__launch_bounds__(256)
__global__ void bn_relu_pool(const float* __restrict__ h, const float* __restrict__ sums,
                             const float* __restrict__ bias,
                             const float* __restrict__ gamma, const float* __restrict__ beta,
                             float* __restrict__ out, int B, int C, int H, int W, int nz)
{
    int Ho = H / 2, Wo = W / 2;
    long total = (long)B * C * Ho * Wo;
    long idx = (long)blockIdx.x * 256 + threadIdx.x;
    if (idx >= total) return;
    int pw = idx % Wo; long t = idx / Wo;
    int ph = t % Ho; t /= Ho;
    int c = t % C; int b = (int)(t / C);

    float M = (float)B * H * W;
    float mean = sums[c] / M;
    float var  = sums[C + c] / M - mean * mean;
    float scale = gamma[c] * rsqrtf(var + 1e-5f);
    float shift = beta[c] - mean * scale + bias[c] * scale;  // fold conv bias

    long zstride = (long)B * C * H * W;
    const float* hp = h + ((long)b * C + c) * H * W;
    float m = 0.f;  // post-relu >= 0
    #pragma unroll
    for (int i = 0; i < 2; ++i)
        #pragma unroll
        for (int j = 0; j < 2; ++j) {
            long off = (2 * ph + i) * W + 2 * pw + j;
            float v = 0.f;
            for (int z = 0; z < nz; ++z) v += hp[z * zstride + off];
            v = v * scale + shift;
            m = fmaxf(m, v);
        }
    out[idx] = m;
}

extern "C" void kernel_launch(void* const* d_in, const int* in_sizes, int n_in,
                              void* d_out, int out_size, void* d_ws, size_t ws_size,
                              hipStream_t stream) {
    const float* x     = (const float*)d_in[0];
    const float* ln_w1 = (const float*)d_in[1];  const float* ln_b1 = (const float*)d_in[2];
    const float* Wb1   = (const float*)d_in[3];  const float* bb1   = (const float*)d_in[4];
    const float* Ws1   = (const float*)d_in[5];  const float* g1    = (const float*)d_in[6];
    const float* be1   = (const float*)d_in[7];
    const float* ln_w2 = (const float*)d_in[8];  const float* ln_b2 = (const float*)d_in[9];
    const float* Wb2   = (const float*)d_in[10]; const float* bb2   = (const float*)d_in[11];
    const float* Ws2   = (const float*)d_in[12]; const float* g2    = (const float*)d_in[13];
    const float* be2   = (const float*)d_in[14];
    const float* ln_w3 = (const float*)d_in[15]; const float* ln_b3 = (const float*)d_in[16];
    const float* Wb3   = (const float*)d_in[17]; const float* bb3   = (const float*)d_in[18];
    const float* Ws3   = (const float*)d_in[19]; const float* g3    = (const float*)d_in[20];
    const float* be3   = (const float*)d_in[21];

    const int B = 32;
    char* ws = (char*)d_ws;
    float*  convbuf = (float*)(ws + 0);              // 33,554,432 (z-partials L2/L3)
    float*  poolbuf = (float*)(ws + 33554432);       //  8,388,608
    float*  stats1  = (float*)(ws + 41943040);       //  2048 x3
    float*  stats2  = (float*)(ws + 41945088);
    float*  stats3  = (float*)(ws + 41947136);
    half_t* wt1     = (half_t*)(ws + 41949184);      //   221,184  (27 x 64 x 64)
    half_t* wt2     = (half_t*)(ws + 42170368);      // 1,327,104  (81 x 128 x 64)
    half_t* wt3     = (half_t*)(ws + 43497472);      // 5,308,416  (162 x 256 x 64)
    half_t* pnbuf   = (half_t*)(ws + 48805888);      // 37,748,736 (max 131072x144)
    half_t* spbuf   = (half_t*)(ws + 86554624);      // 37,748,736
    // total: 124,303,360 B

    hipMemsetAsync(stats1, 0, 6144, stream);

    conv_w<144, 64><<<(64 * 27 * 64 + 255) / 256, 256, 0, stream>>>(Ws1, Wb1, wt1);
    conv_w<576, 128><<<(128 * 81 * 64 + 255) / 256, 256, 0, stream>>>(Ws2, Wb2, wt2);
    conv_w<1152, 256><<<(256 * 162 * 64 + 255) / 256, 256, 0, stream>>>(Ws3, Wb3, wt3);

    // ---------------- layer 1: C=16, H=W=64, OUT=64, NB=1, y=1, z=1 ---------
    {
        const int H = 64, W = 64, OUT = 64;
        int npix = B * H * W;                    // 131072
        ln_prep<16, H, W><<<npix / 16, 256, 0, stream>>>(x, ln_w1, ln_b1, pnbuf, spbuf);
        kan_gemm<144, OUT, H * W, 1, 1><<<dim3(npix / 64, 1, 1), 256, 0, stream>>>(
            pnbuf, spbuf, wt1, convbuf);
        bn_stats<<<dim3(64, OUT), 256, 0, stream>>>(convbuf, bb1, OUT, H * W, B, 1, stats1);
        long tot = (long)B * OUT * (H / 2) * (W / 2);
        bn_relu_pool<<<(tot + 255) / 256, 256, 0, stream>>>(
            convbuf, stats1, bb1, g1, be1, poolbuf, B, OUT, H, W, 1);
    }
    // ---------------- layer 2: C=64, H=W=32, OUT=128, NB=2, y=1, z=2 --------
    {
        const int H = 32, W = 32, OUT = 128;
        int npix = B * H * W;                    // 32768
        ln_prep<64, H, W><<<npix / 16, 256, 0, stream>>>(poolbuf, ln_w2, ln_b2, pnbuf, spbuf);
        kan_gemm<576, OUT, H * W, 2, 2><<<dim3(npix / 64, 1, 2), 256, 0, stream>>>(
            pnbuf, spbuf, wt2, convbuf);           // 2 x 16.8 MB partials in convbuf
        bn_stats<<<dim3(16, OUT), 256, 0, stream>>>(convbuf, bb2, OUT, H * W, B, 2, stats2);
        long tot = (long)B * OUT * (H / 2) * (W / 2);
        bn_relu_pool<<<(tot + 255) / 256, 256, 0, stream>>>(
            convbuf, stats2, bb2, g2, be2, poolbuf, B, OUT, H, W, 2);
    }
    // ---------------- layer 3: C=128, H=W=16, OUT=256, NB=2, y=2, z=4 -------
    {
        const int H = 16, W = 16, OUT = 256;
        int npix = B * H * W;                    // 8192
        ln_prep<128, H, W><<<npix / 16, 256, 0, stream>>>(poolbuf, ln_w3, ln_b3, pnbuf, spbuf);
        kan_gemm<1152, OUT, H * W, 2, 4><<<dim3(npix / 64, 2, 4), 256, 0, stream>>>(
            pnbuf, spbuf, wt3, convbuf);           // 4 x 8.4 MB partials in convbuf
        bn_stats<<<dim3(8, OUT), 256, 0, stream>>>(convbuf, bb3, OUT, H * W, B, 4, stats3);
        long tot = (long)B * OUT * (H / 2) * (W / 2);  // 524288 == out_size
        bn_relu_pool<<<(tot + 255) / 256, 256, 0, stream>>>(
            convbuf, stats3, bb3, g3, be3, (float*)d_out, B, OUT, H, W, 4);
    }
}